// Round 12
// baseline (133.632 us; speedup 1.0000x reference)
//
#include <hip/hip_runtime.h>
#include <hip/hip_fp16.h>

// HDP-HMM forward-backward, exact-semantics parallel decomposition. R12:
//  - fwd/bwd PAIRED scan blocks: 16 fwd + 16 bwd groups per 256-thr block cover
//    the SAME 16-chunk E window -> second direction reads E from L1/L2, E HBM
//    fetch ~halves (was 39MB; E itself is only 21MB)
//  - Ln=8/Wn=8 -> 32768 chunks/dir, 8192 waves = 4/SIMD (was 2/SIMD, occ 29%)
//  - scale reworked for Ln=8; combine PG=32; numerics identical to R11
//    (E must stay f32: fp16/bf16 E underflows 1e-13 / accumulates ~1 in ll)

namespace {
constexpr int Tn = 262144;
constexpr int Kn = 20;
constexpr int Fn = 16;
constexpr float EPSF = 1e-10f;
constexpr float TINY = 1e-35f;

constexpr int Ln3 = 8;
constexpr int Wn3 = 8;
constexpr int NC3 = Tn / Ln3;          // 32768 chunks per direction
constexpr int NBP = NC3 / 16;          // 2048 paired scan blocks (16 chunks, both dirs)
constexpr int NSCG = 16;               // chunks per scale block
constexpr int NBSC = NC3 / NSCG;       // 2048 scale blocks per direction
constexpr int SPC = Ln3 * Kn;          // floats per chunk slot in out = 160

// ws layout (floats); ~23.5 MB
constexpr size_t OFF_P    = 0;
constexpr size_t OFF_W    = 400;
constexpr size_t OFF_CK   = 420;
constexpr size_t OFF_MVIV = 440;
constexpr size_t OFF_E    = 1152;
constexpr size_t OFF_MF   = OFF_E + (size_t)Tn*20 + 128;
constexpr size_t OFF_MB   = OFF_MF + (size_t)Tn;
constexpr size_t OFF_MATF = OFF_MB + (size_t)Tn;
constexpr size_t OFF_MATB = OFF_MATF + 4*(size_t)NC3;
constexpr size_t OFF_SF   = OFF_MATB + 4*(size_t)NC3;
constexpr size_t OFF_SB   = OFF_SF + NC3;
constexpr size_t OFF_END  = OFF_SB + NC3;
}

#if __has_builtin(__builtin_amdgcn_rcpf)
#define FRCP(x) __builtin_amdgcn_rcpf(x)
#else
#define FRCP(x) (1.0f/(x))
#endif

template<int CTRL>
__device__ __forceinline__ float dpp_add(float v) {
  int s = __builtin_amdgcn_update_dpp(0, __float_as_int(v), CTRL, 0xF, 0xF, true);
  return v + __int_as_float(s);
}
template<int CTRL>
__device__ __forceinline__ float dppmov(float v) {
  return __int_as_float(__builtin_amdgcn_update_dpp(0, __float_as_int(v), CTRL, 0xF, 0xF, true));
}

// Sum across each 8-lane group, broadcast. xor1, xor2, half-mirror.
__device__ __forceinline__ float reduce8(float v) {
  v = dpp_add<0xB1>(v);
  v = dpp_add<0x4E>(v);
  v = dpp_add<0x141>(v);
  return v;
}

// ============================ prep ============================
__global__ __launch_bounds__(64) void prep_kernel(
    const float* beta_logits, const float* pi_logits,
    const float* means, const float* log_vars, float* ws)
{
  int k = threadIdx.x;
  if (k < Kn) {
    float row[Kn];
    float mx = -1e30f;
#pragma unroll
    for (int j = 0; j < Kn; ++j) { row[j] = pi_logits[k*Kn + j]; mx = fmaxf(mx, row[j]); }
    float s = 0.f;
#pragma unroll
    for (int j = 0; j < Kn; ++j) { row[j] = expf(row[j] - mx); s += row[j]; }
    float invs = 1.0f / s;
#pragma unroll
    for (int j = 0; j < Kn; ++j) ws[OFF_P + k*Kn + j] = row[j] * invs;
    float ck = 0.f;
#pragma unroll
    for (int f = 0; f < Fn; ++f) {
      float lv  = log_vars[k*Fn + f];
      float var = expf(lv) + 1e-6f;
      float iv  = 1.0f / var;
      float mu  = means[k*Fn + f];
      ((float2*)(ws + OFF_MVIV))[k*Fn + f] = make_float2(mu * iv, iv);
      ck += mu*mu*iv + logf(6.2831853071795864f * var);
    }
    ws[OFF_CK + k] = ck;
  } else if (k == Kn) {
    float cp = 1.f;
#pragma unroll
    for (int i = 0; i < Kn; ++i) {
      float b = 1.0f / (1.0f + expf(-beta_logits[i]));
      ws[OFF_W + i] = b * cp;
      cp *= (1.0f - b);
    }
  }
}

// ============================ emission ============================
__global__ __launch_bounds__(320) void emis_kernel(const float* __restrict__ obs, float* ws)
{
  __shared__ __align__(16) float so[64][20];
  __shared__ __align__(16) float scm[16][24];
  __shared__ __align__(16) float scv[16][24];
  __shared__ __align__(16) float sck[20];
  const int tid = threadIdx.x;
  const int t0 = blockIdx.x * 64;

  if (tid < 256) {
    float4 v = ((const float4*)(obs + (size_t)t0 * Fn))[tid];
    int r = tid >> 2, j = tid & 3;
    *(float4*)&so[r][j*4] = v;
  } else {
    int i = tid - 256;
#pragma unroll
    for (int q = 0; q < 5; ++q) {
      int idx = i * 5 + q;
      float2 c2 = ((const float2*)(ws + OFF_MVIV))[idx];
      int k = idx >> 4, f = idx & 15;
      scm[f][k] = c2.x;
      scv[f][k] = c2.y;
    }
    if (i < Kn) sck[i] = ws[OFF_CK + i];
  }
  __syncthreads();

  const int tl = tid / 5;
  const int k0 = (tid - tl*5) * 4;

  float o[16];
  *(float4*)&o[0]  = *(const float4*)&so[tl][0];
  *(float4*)&o[4]  = *(const float4*)&so[tl][4];
  *(float4*)&o[8]  = *(const float4*)&so[tl][8];
  *(float4*)&o[12] = *(const float4*)&so[tl][12];

  float s1x=0.f,s1y=0.f,s1z=0.f,s1w=0.f;
  float s2x=0.f,s2y=0.f,s2z=0.f,s2w=0.f;
#pragma unroll
  for (int f = 0; f < Fn; ++f) {
    float4 cm = *(const float4*)&scm[f][k0];
    float4 cv = *(const float4*)&scv[f][k0];
    float ov = o[f];
    s1x = fmaf(cv.x * ov, ov, s1x); s2x = fmaf(cm.x, ov, s2x);
    s1y = fmaf(cv.y * ov, ov, s1y); s2y = fmaf(cm.y, ov, s2y);
    s1z = fmaf(cv.z * ov, ov, s1z); s2z = fmaf(cm.z, ov, s2z);
    s1w = fmaf(cv.w * ov, ov, s1w); s2w = fmaf(cm.w, ov, s2w);
  }
  float4 ckv = *(const float4*)&sck[k0];
  float4 rr;
  rr.x = __expf(fmaf(-0.5f, s1x + ckv.x, s2x));
  rr.y = __expf(fmaf(-0.5f, s1y + ckv.y, s2y));
  rr.z = __expf(fmaf(-0.5f, s1z + ckv.z, s2z));
  rr.w = __expf(fmaf(-0.5f, s1w + ckv.w, s2w));
  *(float4*)(ws + OFF_E + (size_t)(t0 + tl)*20 + k0) = rr;
}

// ============ scan (paired fwd/bwd, 8-lane groups, DPP all-gather) ==========
// Block = 256 thr = 32 groups. Groups 0-15: fwd chunks c0..c0+15; groups 16-31:
// bwd chunks c0..c0+15 (same E window -> L1/L2 reuse). Lane j owns states
// j, 8+j, 16+(j&3) (last 4 duplicated on lanes 4-7).
__global__ __launch_bounds__(256, 4) void scan7_kernel(float* ws, float* out)
{
  const int tid = threadIdx.x;
  const int g   = tid >> 3;        // 0..31
  const int j   = tid & 7;
  const int q   = j & 3;
  const int s1i = 8 + j;
  const int s2i = 16 + q;
  const bool isF = (g < 16);
  const int c = (int)blockIdx.x * 16 + (g & 15);
  const float* E = ws + OFF_E;

  float PA0[8], PB0[8], PA1[8], PB1[8], PA2[8], PB2[8];
  float PC0[4], PC1[4], PC2[4];
  {
    const int M[8] = {0,1,2,3,7,6,5,4};
#pragma unroll
    for (int i = 0; i < 8; ++i) {
      int ka = j ^ M[i];
      int kb = 8 + ka;
      if (isF) {
        PA0[i] = ws[OFF_P + ka*Kn + j];
        PB0[i] = ws[OFF_P + kb*Kn + j];
        PA1[i] = ws[OFF_P + ka*Kn + s1i];
        PB1[i] = ws[OFF_P + kb*Kn + s1i];
        PA2[i] = ws[OFF_P + ka*Kn + s2i];
        PB2[i] = ws[OFF_P + kb*Kn + s2i];
      } else {
        PA0[i] = ws[OFF_P + j*Kn + ka];
        PB0[i] = ws[OFF_P + j*Kn + kb];
        PA1[i] = ws[OFF_P + s1i*Kn + ka];
        PB1[i] = ws[OFF_P + s1i*Kn + kb];
        PA2[i] = ws[OFF_P + s2i*Kn + ka];
        PB2[i] = ws[OFF_P + s2i*Kn + kb];
      }
    }
#pragma unroll
    for (int i = 0; i < 4; ++i) {
      int kc = 16 + (q ^ i);
      if (isF) {
        PC0[i] = ws[OFF_P + kc*Kn + j];
        PC1[i] = ws[OFF_P + kc*Kn + s1i];
        PC2[i] = ws[OFF_P + kc*Kn + s2i];
      } else {
        PC0[i] = ws[OFF_P + j*Kn + kc];
        PC1[i] = ws[OFF_P + s1i*Kn + kc];
        PC2[i] = ws[OFF_P + s2i*Kn + kc];
      }
    }
  }

  float Ma = 1.f, Mc = 0.f, Md = 1.f;
  float* mArr = ws + (isF ? OFF_MF : OFF_MB);
  unsigned* uS = (unsigned*)(out + (isF ? (size_t)0 : (size_t)Tn * Kn) + (size_t)c * SPC);

  auto mobius = [&](float m) {
    float na = m * Ma;
    float nc = fmaf(EPSF, Mc, na);
    float nd = EPSF * Md;
    float mx = fmaxf(nc, nd);
    float lam = (mx > 0.f) ? FRCP(mx) : 1.0f;
    Ma = na*lam; Mc = nc*lam; Md = nd*lam;
  };
  auto packh2 = [](float a, float b) -> unsigned {
    __half2 h2 = __floats2half2_rn(a, b);
    return *(unsigned*)&h2;
  };
  auto xmv = [&](float w0, float w1, float w2, float& r0, float& r1, float& r2) {
    float x10 = dppmov<0xB1>(w0),  x11 = dppmov<0xB1>(w1),  x12 = dppmov<0xB1>(w2);
    float x20 = dppmov<0x4E>(w0),  x21 = dppmov<0x4E>(w1),  x22 = dppmov<0x4E>(w2);
    float x30 = dppmov<0x1B>(w0),  x31 = dppmov<0x1B>(w1),  x32 = dppmov<0x1B>(w2);
    float m0  = dppmov<0x141>(w0), m1  = dppmov<0x141>(w1);
    float m01 = dppmov<0xB1>(m0),  m11 = dppmov<0xB1>(m1);
    float m02 = dppmov<0x4E>(m0),  m12 = dppmov<0x4E>(m1);
    float m03 = dppmov<0x1B>(m0),  m13 = dppmov<0x1B>(m1);
#define ACC3(PA, PB, PC, OUT)                                             \
    {                                                                     \
      float a  = w0 * PA[0],  b = x10 * PA[1];                            \
      a = fmaf(x20, PA[2], a); b = fmaf(x30, PA[3], b);                   \
      a = fmaf(m0,  PA[4], a); b = fmaf(m01, PA[5], b);                   \
      a = fmaf(m02, PA[6], a); b = fmaf(m03, PA[7], b);                   \
      a = fmaf(w1,  PB[0], a); b = fmaf(x11, PB[1], b);                   \
      a = fmaf(x21, PB[2], a); b = fmaf(x31, PB[3], b);                   \
      a = fmaf(m1,  PB[4], a); b = fmaf(m11, PB[5], b);                   \
      a = fmaf(m12, PB[6], a); b = fmaf(m13, PB[7], b);                   \
      a = fmaf(w2,  PC[0], a); b = fmaf(x12, PC[1], b);                   \
      a = fmaf(x22, PC[2], a); b = fmaf(x32, PC[3], b);                   \
      OUT = a + b;                                                        \
    }
    ACC3(PA0, PB0, PC0, r0)
    ACC3(PA1, PB1, PC1, r1)
    ACC3(PA2, PB2, PC2, r2)
#undef ACC3
  };

  if (isF) {
    const int bodyStart = c * Ln3;
    const int tend = bodyStart + Ln3 - 1;
    const int t0 = (c == 0) ? 0 : (bodyStart - Wn3);
    float v0, v1, v2;
    {
      float e0i = E[t0*20 + j], e1i = E[t0*20 + s1i], e2i = E[t0*20 + s2i];
      if (c == 0) {
        v0 = ws[OFF_W + j]   * e0i;
        v1 = ws[OFF_W + s1i] * e1i;
        v2 = ws[OFF_W + s2i] * e2i;
      } else {
        v0 = 0.05f * e0i; v1 = 0.05f * e1i; v2 = 0.05f * e2i;
      }
    }
    float sv = reduce8(fmaf(0.5f, v2, v0 + v1));
    float m = sv;
    float iV = (sv > TINY) ? FRCP(sv) : 1.0f;
    if (sv <= TINY) { v0 = 0.05f; v1 = 0.05f; v2 = 0.05f; }
    if (c == 0) {
      mArr[0] = m;
      mobius(m);
      uS[j] = packh2(v0 * iV, v1 * iV);
      uS[8 + q] = packh2(v2 * iV, 0.f);
    }
    float A = m * iV;
    float rho = (m > TINY) ? FRCP(m) : 1.0f;
    // depth-4 shift register: before iter t, (a,b,c,d) = E[t..t+3]
    float e0a = E[(t0+1)*20 + j], e1a = E[(t0+1)*20 + s1i], e2a = E[(t0+1)*20 + s2i];
    float e0b = E[(t0+2)*20 + j], e1b = E[(t0+2)*20 + s1i], e2b = E[(t0+2)*20 + s2i];
    float e0c = E[(t0+3)*20 + j], e1c = E[(t0+3)*20 + s1i], e2c = E[(t0+3)*20 + s2i];
    float e0d = E[(t0+4)*20 + j], e1d = E[(t0+4)*20 + s1i], e2d = E[(t0+4)*20 + s2i];

#define FWD_STEP(REC)                                                     \
    {                                                                     \
      float acc0, acc1, acc2;                                             \
      xmv(v0, v1, v2, acc0, acc1, acc2);                                  \
      float er0 = e0a * rho, er1 = e1a * rho, er2 = e2a * rho;            \
      e0a = e0b; e0b = e0c; e0c = e0d; e0d = E[(t+4)*20 + j];             \
      e1a = e1b; e1b = e1c; e1c = e1d; e1d = E[(t+4)*20 + s1i];           \
      e2a = e2b; e2b = e2c; e2c = e2d; e2d = E[(t+4)*20 + s2i];           \
      v0 = acc0 * er0; v1 = acc1 * er1; v2 = acc2 * er2;                  \
      float sv2 = reduce8(fmaf(0.5f, v2, v0 + v1));                      \
      float mn = sv2 * A;                                                 \
      float iVn = (sv2 > TINY) ? FRCP(sv2) : 1.0f;                        \
      if (sv2 <= TINY) { v0 = 0.05f; v1 = 0.05f; v2 = 0.05f; }            \
      if (REC) {                                                          \
        mArr[t] = mn;                                                     \
        mobius(mn);                                                       \
        int lt = t - bodyStart;                                           \
        uS[lt*12 + j] = packh2(v0 * iVn, v1 * iVn);                       \
        uS[lt*12 + 8 + q] = packh2(v2 * iVn, 0.f);                        \
      }                                                                   \
      A = mn * iVn;                                                       \
      rho = (mn > TINY) ? FRCP(mn) : 1.0f;                                \
    }

    for (int t = t0 + 1; t < bodyStart; ++t) FWD_STEP(false)
    const int bstart2 = (c == 0) ? 1 : bodyStart;
    for (int t = bstart2; t <= tend; ++t) FWD_STEP(true)
#undef FWD_STEP
    ((float4*)(ws + OFF_MATF))[c] = make_float4(Ma, Mc, Md, 0.f);
  } else {
    const int bodyStart = c * Ln3;
    const int top = bodyStart + Ln3 - 1;
    int r0 = top + Wn3; if (r0 > Tn - 1) r0 = Tn - 1;   // r0==Tn-1 => exact init
    float v0 = 0.05f, v1 = 0.05f, v2 = 0.05f;
    float sv = reduce8(fmaf(0.5f, v2, v0 + v1));         // ~1.0
    float iV = (sv > TINY) ? FRCP(sv) : 1.0f;
    float A = iV;
    float rho = 1.0f;
    // depth-4: before iter r, (a,b,c,d) = E[r+1, r, r-1, r-2]
    float e0a = E[r0*20 + j],     e1a = E[r0*20 + s1i],     e2a = E[r0*20 + s2i];
    float e0b = E[(r0-1)*20 + j], e1b = E[(r0-1)*20 + s1i], e2b = E[(r0-1)*20 + s2i];
    float e0c = E[(r0-2)*20 + j], e1c = E[(r0-2)*20 + s1i], e2c = E[(r0-2)*20 + s2i];
    float e0d = E[(r0-3)*20 + j], e1d = E[(r0-3)*20 + s1i], e2d = E[(r0-3)*20 + s2i];

#define BWD_STEP(REC)                                                     \
    {                                                                     \
      float w0 = v0 * e0a, w1 = v1 * e1a, w2 = v2 * e2a;                  \
      float acc0, acc1, acc2;                                             \
      xmv(w0, w1, w2, acc0, acc1, acc2);                                  \
      v0 = acc0 * rho; v1 = acc1 * rho; v2 = acc2 * rho;                  \
      e0a = e0b; e0b = e0c; e0c = e0d; e0d = E[(r-3)*20 + j];             \
      e1a = e1b; e1b = e1c; e1c = e1d; e1d = E[(r-3)*20 + s1i];           \
      e2a = e2b; e2b = e2c; e2c = e2d; e2d = E[(r-3)*20 + s2i];           \
      float sv2 = reduce8(fmaf(0.5f, v2, v0 + v1));                      \
      float mn = sv2 * A;                                                 \
      float iVn = (sv2 > TINY) ? FRCP(sv2) : 1.0f;                        \
      if (sv2 <= TINY) { v0 = 0.05f; v1 = 0.05f; v2 = 0.05f; }            \
      if (REC) {                                                          \
        mArr[r+1] = mn;                                                   \
        mobius(mn);                                                       \
        int lr = r - bodyStart;                                           \
        uS[lr*12 + j] = packh2(v0 * iVn, v1 * iVn);                       \
        uS[lr*12 + 8 + q] = packh2(v2 * iVn, 0.f);                        \
      }                                                                   \
      A = mn * iVn;                                                       \
      rho = (mn > TINY) ? FRCP(mn) : 1.0f;                                \
    }

    for (int r = r0 - 1; r > top; --r) BWD_STEP(false)
    int rb = (r0 - 1 < top) ? (r0 - 1) : top;
    for (int r = rb; r >= bodyStart; --r) BWD_STEP(true)
#undef BWD_STEP
    ((float4*)(ws + OFF_MATB))[NC3 - 1 - c] = make_float4(Ma, Mc, Md, 0.f);
  }
}

// ============================ combine ============================
__global__ __launch_bounds__(1024) void combine4_kernel(float* ws, float* out)
{
  __shared__ float wag[16][3];
  __shared__ float wpre[16][3];
  const bool isF = (blockIdx.x == 0);
  const float4* M4 = (const float4*)(ws + (isF ? OFF_MATF : OFF_MATB));
  float* sArr = ws + (isF ? OFF_SF : OFF_SB);
  const float s0 = isF ? 1.0f : 20.0f;
  constexpr int PG = NC3 / 1024;   // 32
  const int tid  = threadIdx.x;
  const int lane = tid & 63;
  const int wid  = tid >> 6;

  float4 mm[PG];
#pragma unroll
  for (int i = 0; i < PG; ++i) mm[i] = M4[tid*PG + i];

  float a = 1.f, cc = 0.f, d = 1.f;
#pragma unroll
  for (int i = 0; i < PG; ++i) {
    float na = mm[i].x * a;
    float nc = fmaf(mm[i].y, a, mm[i].z * cc);
    float nd = mm[i].z * d;
    float mx = fmaxf(na, fmaxf(nc, nd));
    float lam = (mx > 0.f) ? FRCP(mx) : 1.0f;
    a = na*lam; cc = nc*lam; d = nd*lam;
  }

  float ia = a, ic = cc, id = d;
  for (int off = 1; off < 64; off <<= 1) {
    float pa = __shfl_up(ia, off, 64);
    float pc = __shfl_up(ic, off, 64);
    float pd = __shfl_up(id, off, 64);
    if (lane >= off) {
      float na = ia * pa;
      float nc = fmaf(ic, pa, id * pc);
      float nd = id * pd;
      float mx = fmaxf(na, fmaxf(nc, nd));
      float lam = (mx > 0.f) ? FRCP(mx) : 1.0f;
      ia = na*lam; ic = nc*lam; id = nd*lam;
    }
  }
  if (lane == 63) { wag[wid][0] = ia; wag[wid][1] = ic; wag[wid][2] = id; }
  __syncthreads();

  if (tid == 0) {
    float ea = 1.f, ec = 0.f, ed = 1.f;
#pragma unroll
    for (int w = 0; w < 16; ++w) {
      wpre[w][0] = ea; wpre[w][1] = ec; wpre[w][2] = ed;
      float na = wag[w][0] * ea;
      float nc = fmaf(wag[w][1], ea, wag[w][2] * ec);
      float nd = wag[w][2] * ed;
      float mx = fmaxf(na, fmaxf(nc, nd));
      float lam = (mx > 0.f) ? FRCP(mx) : 1.0f;
      ea = na*lam; ec = nc*lam; ed = nd*lam;
    }
    if (isF) {
      float den = fmaf(ec, s0, ed);
      float sfin = (den > 0.f) ? (ea * s0)/den : 0.f;
      out[(size_t)2 * Tn * Kn] = logf(sfin + EPSF);
    }
  }
  __syncthreads();

  float ea = __shfl_up(ia, 1, 64);
  float ec = __shfl_up(ic, 1, 64);
  float ed = __shfl_up(id, 1, 64);
  if (lane == 0) { ea = 1.f; ec = 0.f; ed = 1.f; }
  float pa = wpre[wid][0], pc = wpre[wid][1], pd = wpre[wid][2];
  float xa = ea * pa;
  float xc = fmaf(ec, pa, ed * pc);
  float xd = ed * pd;

  float num = xa * s0, den = fmaf(xc, s0, xd);
  float s = (den > 0.f) ? num/den : 0.f;
#pragma unroll
  for (int i = 0; i < PG; ++i) {
    sArr[tid*PG + i] = s;
    float nn = mm[i].x * s, dd = fmaf(mm[i].y, s, mm[i].z);
    s = (dd > 0.f) ? nn/dd : 0.f;
  }
}

// ============================ scale ============================
// 128 thr = 16 groups x 8 lanes; lane ll handles row ll of its chunk (Ln3=8).
__global__ __launch_bounds__(128) void scale5_kernel(float* ws, float* out)
{
  const int tid = threadIdx.x;
  const int g   = tid >> 3;
  const int ll  = tid & 7;
  const bool isF = ((int)blockIdx.x < NBSC);
  const int c = (isF ? (int)blockIdx.x : (int)blockIdx.x - NBSC) * NSCG + g;
  float* base = out + (isF ? (size_t)0 : (size_t)Tn * Kn) + (size_t)c * SPC;
  const unsigned* uS = (const unsigned*)base;

  float mySig = 1.0f;
  if (isF) {
    const float* mA = ws + OFF_MF;
    float s = ws[OFF_SF + c];
    const int t0 = c * Ln3;
#pragma unroll
    for (int i = 0; i < Ln3; ++i) {
      float z = s * mA[t0 + i];
      float sn = z * FRCP(z + EPSF);
      if (i == ll) mySig = sn;
      s = sn;
    }
  } else {
    const float* mA = ws + OFF_MB;
    float s = ws[OFF_SB + (NC3 - 1 - c)];
    const int top = c * Ln3 + Ln3 - 1;
#pragma unroll
    for (int i = 0; i < Ln3; ++i) {
      int r = top - i;
      float sn;
      if (r == Tn - 1) sn = s;
      else {
        float z = s * mA[r + 1];
        sn = z * FRCP(z + EPSF);
      }
      if (i == Ln3 - 1 - ll) mySig = sn;
      s = sn;
    }
  }

  uint4 ua = ((const uint4*)(uS + ll*12))[0];
  uint4 ub = ((const uint4*)(uS + ll*12))[1];
  uint4 uc = ((const uint4*)(uS + ll*12))[2];
  __syncthreads();   // staged reads complete before f32 overwrites

  const bool onesRow = (!isF && c == NC3 - 1 && ll == Ln3 - 1);
  float sg = mySig;
  unsigned slots[12] = {ua.x,ua.y,ua.z,ua.w, ub.x,ub.y,ub.z,ub.w, uc.x,uc.y,uc.z,uc.w};
  float o[20];
#pragma unroll
  for (int jj = 0; jj < 8; ++jj) {
    __half2 h2 = *(__half2*)&slots[jj];
    float2 f2 = __half22float2(h2);
    o[jj]     = f2.x * sg;
    o[8 + jj] = f2.y * sg;
  }
#pragma unroll
  for (int qq = 0; qq < 4; ++qq) {
    __half2 h2 = *(__half2*)&slots[8 + qq];
    float2 f2 = __half22float2(h2);
    o[16 + qq] = f2.x * sg;
  }
  if (onesRow) {
#pragma unroll
    for (int k = 0; k < 20; ++k) o[k] = 1.0f;
  }
  float* dst = base + ll * 20;
  *(float4*)&dst[0]  = *(float4*)&o[0];
  *(float4*)&dst[4]  = *(float4*)&o[4];
  *(float4*)&dst[8]  = *(float4*)&o[8];
  *(float4*)&dst[12] = *(float4*)&o[12];
  *(float4*)&dst[16] = *(float4*)&o[16];
}

extern "C" void kernel_launch(void* const* d_in, const int* in_sizes, int n_in,
                              void* d_out, int out_size, void* d_ws, size_t ws_size,
                              hipStream_t stream) {
  const float* obs         = (const float*)d_in[0];
  const float* beta_logits = (const float*)d_in[1];
  const float* pi_logits   = (const float*)d_in[2];
  const float* means       = (const float*)d_in[3];
  const float* log_vars    = (const float*)d_in[4];
  float* out = (float*)d_out;
  float* ws  = (float*)d_ws;

  hipLaunchKernelGGL(prep_kernel, dim3(1), dim3(64), 0, stream,
                     beta_logits, pi_logits, means, log_vars, ws);
  hipLaunchKernelGGL(emis_kernel, dim3(Tn/64), dim3(320), 0, stream, obs, ws);
  hipLaunchKernelGGL(scan7_kernel, dim3(NBP), dim3(256), 0, stream, ws, out);
  hipLaunchKernelGGL(combine4_kernel, dim3(2), dim3(1024), 0, stream, ws, out);
  hipLaunchKernelGGL(scale5_kernel, dim3(2*NBSC), dim3(128), 0, stream, ws, out);
}

// Round 13
// 93.911 us; speedup vs baseline: 1.4230x; 1.4230x over previous
//
#include <hip/hip_runtime.h>
#include <hip/hip_fp16.h>

// HDP-HMM forward-backward, exact-semantics parallel decomposition. R13:
//  - DUAL-CHAIN scan: each 8-lane group runs TWO independent chunk recursions
//    (cA=2i, cB=2i+1, same direction, shared P constants) interleaved in one
//    loop -> 2x ILP fills the reduce->rcp->v dependency-chain stalls that kept
//    scan at ~45us across R7-R11 (VALUBusy ~50%).
//  - boundary chunks (fwd c=0, bwd c=NC-1) unified into the same 23-iter loop
//    via per-step reset-selects (v = init ? w*e : acc*e*rho; A,rho -> 1);
//    E array padded +-12 rows so virtual warm-up reads never fault.
//  - prep kernel deleted: scan blocks rebuild P/w in LDS; emis computes
//    mviv/ck itself. 4 kernels total.
//  - Ln=16/Wn=8 (R11 config; R12's Ln=8 regressed). scale/combine = R11.

namespace {
constexpr int Tn = 262144;
constexpr int Kn = 20;
constexpr int Fn = 16;
constexpr float EPSF = 1e-10f;
constexpr float TINY = 1e-35f;

constexpr int Ln3 = 16;
constexpr int Wn3 = 8;               // (structural: warm-up length baked into loop)
constexpr int NC3 = Tn / Ln3;        // 16384 chunks per direction
constexpr int NBF8 = NC3 / 2 / 32;   // 256 scan blocks per direction (32 groups x 2 chunks)
constexpr int NBSC = NC3 / 8;        // 2048 scale blocks per direction
constexpr int SPC = Ln3 * Kn;        // floats per chunk slot in out = 320

// ws layout (floats); ~23.7 MB. E has 12-row pads on BOTH sides.
constexpr size_t OFF_E    = 256;                          // rows -12..-1 are pad
constexpr size_t OFF_MF   = OFF_E + (size_t)Tn*20 + 256;  // + back pad
constexpr size_t OFF_MB   = OFF_MF + (size_t)Tn;
constexpr size_t OFF_MATF = OFF_MB + (size_t)Tn;
constexpr size_t OFF_MATB = OFF_MATF + 4*(size_t)NC3;
constexpr size_t OFF_SF   = OFF_MATB + 4*(size_t)NC3;
constexpr size_t OFF_SB   = OFF_SF + NC3;
constexpr size_t OFF_END  = OFF_SB + NC3;
}

#if __has_builtin(__builtin_amdgcn_rcpf)
#define FRCP(x) __builtin_amdgcn_rcpf(x)
#else
#define FRCP(x) (1.0f/(x))
#endif

template<int CTRL>
__device__ __forceinline__ float dpp_add(float v) {
  int s = __builtin_amdgcn_update_dpp(0, __float_as_int(v), CTRL, 0xF, 0xF, true);
  return v + __int_as_float(s);
}
template<int CTRL>
__device__ __forceinline__ float dppmov(float v) {
  return __int_as_float(__builtin_amdgcn_update_dpp(0, __float_as_int(v), CTRL, 0xF, 0xF, true));
}

// Sum across each 8-lane group, broadcast. xor1, xor2, half-mirror.
__device__ __forceinline__ float reduce8(float v) {
  v = dpp_add<0xB1>(v);
  v = dpp_add<0x4E>(v);
  v = dpp_add<0x141>(v);
  return v;
}

__device__ __forceinline__ unsigned packh2(float a, float b) {
  __half2 h2 = __floats2half2_rn(a, b);
  return *(unsigned*)&h2;
}

// ============================ emission (prep fused) ============================
__global__ __launch_bounds__(320) void emis_kernel(
    const float* __restrict__ obs, const float* __restrict__ means,
    const float* __restrict__ log_vars, float* ws)
{
  __shared__ __align__(16) float so[64][20];
  __shared__ __align__(16) float scm[16][24];
  __shared__ __align__(16) float scv[16][24];
  __shared__ __align__(16) float sck[20];
  const int tid = threadIdx.x;
  const int t0 = blockIdx.x * 64;

  if (tid < 256) {
    float4 v = ((const float4*)(obs + (size_t)t0 * Fn))[tid];
    int r = tid >> 2, j = tid & 3;
    *(float4*)&so[r][j*4] = v;
  } else {
    int i = tid - 256;                 // 0..63
    if (i < Kn) {
      float ck = 0.f;
#pragma unroll
      for (int f = 0; f < Fn; ++f) {
        float lv  = log_vars[i*Fn + f];
        float var = expf(lv) + 1e-6f;
        float iv  = 1.0f / var;
        float mu  = means[i*Fn + f];
        scm[f][i] = mu * iv;
        scv[f][i] = iv;
        ck += mu*mu*iv + logf(6.2831853071795864f * var);
      }
      sck[i] = ck;
    }
  }
  __syncthreads();

  const int tl = tid / 5;
  const int k0 = (tid - tl*5) * 4;

  float o[16];
  *(float4*)&o[0]  = *(const float4*)&so[tl][0];
  *(float4*)&o[4]  = *(const float4*)&so[tl][4];
  *(float4*)&o[8]  = *(const float4*)&so[tl][8];
  *(float4*)&o[12] = *(const float4*)&so[tl][12];

  float s1x=0.f,s1y=0.f,s1z=0.f,s1w=0.f;
  float s2x=0.f,s2y=0.f,s2z=0.f,s2w=0.f;
#pragma unroll
  for (int f = 0; f < Fn; ++f) {
    float4 cm = *(const float4*)&scm[f][k0];
    float4 cv = *(const float4*)&scv[f][k0];
    float ov = o[f];
    s1x = fmaf(cv.x * ov, ov, s1x); s2x = fmaf(cm.x, ov, s2x);
    s1y = fmaf(cv.y * ov, ov, s1y); s2y = fmaf(cm.y, ov, s2y);
    s1z = fmaf(cv.z * ov, ov, s1z); s2z = fmaf(cm.z, ov, s2z);
    s1w = fmaf(cv.w * ov, ov, s1w); s2w = fmaf(cm.w, ov, s2w);
  }
  float4 ckv = *(const float4*)&sck[k0];
  float4 rr;
  rr.x = __expf(fmaf(-0.5f, s1x + ckv.x, s2x));
  rr.y = __expf(fmaf(-0.5f, s1y + ckv.y, s2y));
  rr.z = __expf(fmaf(-0.5f, s1z + ckv.z, s2z));
  rr.w = __expf(fmaf(-0.5f, s1w + ckv.w, s2w));
  *(float4*)(ws + OFF_E + (size_t)(t0 + tl)*20 + k0) = rr;
}

// ============ scan: dual-chain 8-lane groups, DPP all-gather ============
// Block = 256 thr = 32 groups; group g handles chunks (2*pairI, 2*pairI+1)
// of one direction. Lane j owns states j, 8+j, 16+(j&3).
__global__ __launch_bounds__(256) void scan8_kernel(
    const float* __restrict__ beta_logits, const float* __restrict__ pi_logits,
    float* ws, float* out)
{
  __shared__ __align__(16) float Psh[Kn*Kn];
  __shared__ float wsh[Kn];
  const int tid = threadIdx.x;
  if (tid < Kn) {
    float row[Kn]; float mx = -1e30f;
#pragma unroll
    for (int jj = 0; jj < Kn; ++jj) { row[jj] = pi_logits[tid*Kn + jj]; mx = fmaxf(mx, row[jj]); }
    float s = 0.f;
#pragma unroll
    for (int jj = 0; jj < Kn; ++jj) { row[jj] = expf(row[jj] - mx); s += row[jj]; }
    float invs = 1.0f / s;
#pragma unroll
    for (int jj = 0; jj < Kn; ++jj) Psh[tid*Kn + jj] = row[jj] * invs;
  } else if (tid == Kn) {
    float cp = 1.f;
#pragma unroll
    for (int i = 0; i < Kn; ++i) {
      float b = 1.0f / (1.0f + expf(-beta_logits[i]));
      wsh[i] = b * cp;
      cp *= (1.0f - b);
    }
  }
  __syncthreads();

  const int g   = tid >> 3;
  const int j   = tid & 7;
  const int q   = j & 3;
  const int s1i = 8 + j;
  const int s2i = 16 + q;
  const bool isF = ((int)blockIdx.x < NBF8);
  const int pairI = (isF ? (int)blockIdx.x : (int)blockIdx.x - NBF8) * 32 + g;
  const int cA = pairI * 2, cB = cA + 1;
  const float* E = ws + OFF_E;

  float PA0[8], PB0[8], PA1[8], PB1[8], PA2[8], PB2[8];
  float PC0[4], PC1[4], PC2[4];
  {
    const int M[8] = {0,1,2,3,7,6,5,4};
#pragma unroll
    for (int i = 0; i < 8; ++i) {
      int ka = j ^ M[i];
      int kb = 8 + ka;
      if (isF) {
        PA0[i] = Psh[ka*Kn + j];   PB0[i] = Psh[kb*Kn + j];
        PA1[i] = Psh[ka*Kn + s1i]; PB1[i] = Psh[kb*Kn + s1i];
        PA2[i] = Psh[ka*Kn + s2i]; PB2[i] = Psh[kb*Kn + s2i];
      } else {
        PA0[i] = Psh[j*Kn + ka];   PB0[i] = Psh[j*Kn + kb];
        PA1[i] = Psh[s1i*Kn + ka]; PB1[i] = Psh[s1i*Kn + kb];
        PA2[i] = Psh[s2i*Kn + ka]; PB2[i] = Psh[s2i*Kn + kb];
      }
    }
#pragma unroll
    for (int i = 0; i < 4; ++i) {
      int kc = 16 + (q ^ i);
      if (isF) {
        PC0[i] = Psh[kc*Kn + j]; PC1[i] = Psh[kc*Kn + s1i]; PC2[i] = Psh[kc*Kn + s2i];
      } else {
        PC0[i] = Psh[j*Kn + kc]; PC1[i] = Psh[s1i*Kn + kc]; PC2[i] = Psh[s2i*Kn + kc];
      }
    }
  }
  const float w0c = wsh[j], w1c = wsh[s1i], w2c = wsh[s2i];

  float MaA=1.f, McA=0.f, MdA=1.f, MaB=1.f, McB=0.f, MdB=1.f;
  float* mArr = ws + (isF ? OFF_MF : OFF_MB);
  unsigned* uSA = (unsigned*)(out + (isF ? (size_t)0 : (size_t)Tn * Kn) + (size_t)cA * SPC);
  unsigned* uSB = uSA + SPC;

  auto mobius = [&](float m, float& Ma, float& Mc, float& Md) {
    float na = m * Ma;
    float nc = fmaf(EPSF, Mc, na);
    float nd = EPSF * Md;
    float mx = fmaxf(nc, nd);
    float lam = (mx > 0.f) ? FRCP(mx) : 1.0f;
    Ma = na*lam; Mc = nc*lam; Md = nd*lam;
  };
  auto xmv = [&](float w0, float w1, float w2, float& r0, float& r1, float& r2) {
    float x10 = dppmov<0xB1>(w0),  x11 = dppmov<0xB1>(w1),  x12 = dppmov<0xB1>(w2);
    float x20 = dppmov<0x4E>(w0),  x21 = dppmov<0x4E>(w1),  x22 = dppmov<0x4E>(w2);
    float x30 = dppmov<0x1B>(w0),  x31 = dppmov<0x1B>(w1),  x32 = dppmov<0x1B>(w2);
    float m0  = dppmov<0x141>(w0), m1  = dppmov<0x141>(w1);
    float m01 = dppmov<0xB1>(m0),  m11 = dppmov<0xB1>(m1);
    float m02 = dppmov<0x4E>(m0),  m12 = dppmov<0x4E>(m1);
    float m03 = dppmov<0x1B>(m0),  m13 = dppmov<0x1B>(m1);
#define ACC3(PA, PB, PC, OUT)                                             \
    {                                                                     \
      float a  = w0 * PA[0],  b = x10 * PA[1];                            \
      a = fmaf(x20, PA[2], a); b = fmaf(x30, PA[3], b);                   \
      a = fmaf(m0,  PA[4], a); b = fmaf(m01, PA[5], b);                   \
      a = fmaf(m02, PA[6], a); b = fmaf(m03, PA[7], b);                   \
      a = fmaf(w1,  PB[0], a); b = fmaf(x11, PB[1], b);                   \
      a = fmaf(x21, PB[2], a); b = fmaf(x31, PB[3], b);                   \
      a = fmaf(m1,  PB[4], a); b = fmaf(m11, PB[5], b);                   \
      a = fmaf(m12, PB[6], a); b = fmaf(m13, PB[7], b);                   \
      a = fmaf(w2,  PC[0], a); b = fmaf(x12, PC[1], b);                   \
      a = fmaf(x22, PC[2], a); b = fmaf(x32, PC[3], b);                   \
      OUT = a + b;                                                        \
    }
    ACC3(PA0, PB0, PC0, r0)
    ACC3(PA1, PB1, PC1, r1)
    ACC3(PA2, PB2, PC2, r2)
#undef ACC3
  };

  if (isF) {
    const int bSA = cA * Ln3;                 // bSB = bSA + 16
    const bool c0 = (cA == 0);
    // virtual inits at rows bSA-8 (A; garbage for c0, reset at t==0) and bSA+8 (B)
    float vA0, vA1, vA2, vB0, vB1, vB2;
    {
      const float* p0 = E + (ptrdiff_t)(bSA - 8) * 20;
      vA0 = 0.05f * p0[j]; vA1 = 0.05f * p0[s1i]; vA2 = 0.05f * p0[s2i];
      const float* p1 = E + (ptrdiff_t)(bSA + 8) * 20;
      vB0 = 0.05f * p1[j]; vB1 = 0.05f * p1[s1i]; vB2 = 0.05f * p1[s2i];
    }
    float svA = reduce8(fmaf(0.5f, vA2, vA0 + vA1));
    float iVA = (svA > TINY) ? FRCP(svA) : 1.0f;
    if (svA <= TINY) { vA0 = vA1 = vA2 = 0.05f; }
    float AA = svA * iVA;
    float rhoA = (svA > TINY) ? FRCP(svA) : 1.0f;
    float svB = reduce8(fmaf(0.5f, vB2, vB0 + vB1));
    float iVB = (svB > TINY) ? FRCP(svB) : 1.0f;
    if (svB <= TINY) { vB0 = vB1 = vB2 = 0.05f; }
    float AB = svB * iVB;
    float rhoB = (svB > TINY) ? FRCP(svB) : 1.0f;

    const float* pA = E + (ptrdiff_t)(bSA - 7) * 20;
    float eA0a = pA[j], eA1a = pA[s1i], eA2a = pA[s2i]; pA += 20;
    float eA0b = pA[j], eA1b = pA[s1i], eA2b = pA[s2i]; pA += 20;
    float eA0c = pA[j], eA1c = pA[s1i], eA2c = pA[s2i]; pA += 20;
    const float* pB = E + (ptrdiff_t)(bSA + 9) * 20;
    float eB0a = pB[j], eB1a = pB[s1i], eB2a = pB[s2i]; pB += 20;
    float eB0b = pB[j], eB1b = pB[s1i], eB2b = pB[s2i]; pB += 20;
    float eB0c = pB[j], eB1c = pB[s1i], eB2c = pB[s2i]; pB += 20;

    for (int i = 0; i < 23; ++i) {
      const int t = bSA - 7 + i;
      float accA0, accA1, accA2, accB0, accB1, accB2;
      xmv(vA0, vA1, vA2, accA0, accA1, accA2);
      xmv(vB0, vB1, vB2, accB0, accB1, accB2);
      float ea0 = eA0a, ea1 = eA1a, ea2 = eA2a;
      float eb0 = eB0a, eb1 = eB1a, eb2 = eB2a;
      eA0a = eA0b; eA0b = eA0c; eA0c = pA[j];
      eA1a = eA1b; eA1b = eA1c; eA1c = pA[s1i];
      eA2a = eA2b; eA2b = eA2c; eA2c = pA[s2i]; pA += 20;
      eB0a = eB0b; eB0b = eB0c; eB0c = pB[j];
      eB1a = eB1b; eB1b = eB1c; eB1c = pB[s1i];
      eB2a = eB2b; eB2b = eB2c; eB2c = pB[s2i]; pB += 20;
      const bool init0 = c0 && (t == 0);
      vA0 = init0 ? (w0c * ea0) : (accA0 * (ea0 * rhoA));
      vA1 = init0 ? (w1c * ea1) : (accA1 * (ea1 * rhoA));
      vA2 = init0 ? (w2c * ea2) : (accA2 * (ea2 * rhoA));
      vB0 = accB0 * (eb0 * rhoB);
      vB1 = accB1 * (eb1 * rhoB);
      vB2 = accB2 * (eb2 * rhoB);
      float sA = reduce8(fmaf(0.5f, vA2, vA0 + vA1));
      float sB = reduce8(fmaf(0.5f, vB2, vB0 + vB1));
      float mnA = sA * (init0 ? 1.0f : AA);
      float mnB = sB * AB;
      float iVnA = (sA > TINY) ? FRCP(sA) : 1.0f;
      float iVnB = (sB > TINY) ? FRCP(sB) : 1.0f;
      if (sA <= TINY) { vA0 = vA1 = vA2 = 0.05f; }
      if (sB <= TINY) { vB0 = vB1 = vB2 = 0.05f; }
      if (i >= 7) {
        const int lt = i - 7;
        mArr[t] = mnA;
        mArr[t + 16] = mnB;
        mobius(mnA, MaA, McA, MdA);
        mobius(mnB, MaB, McB, MdB);
        uSA[lt*12 + j] = packh2(vA0 * iVnA, vA1 * iVnA);
        uSA[lt*12 + 8 + q] = packh2(vA2 * iVnA, 0.f);
        uSB[lt*12 + j] = packh2(vB0 * iVnB, vB1 * iVnB);
        uSB[lt*12 + 8 + q] = packh2(vB2 * iVnB, 0.f);
      }
      AA = mnA * iVnA; AB = mnB * iVnB;
      rhoA = (mnA > TINY) ? FRCP(mnA) : 1.0f;
      rhoB = (mnB > TINY) ? FRCP(mnB) : 1.0f;
    }
    ((float4*)(ws + OFF_MATF))[cA] = make_float4(MaA, McA, MdA, 0.f);
    ((float4*)(ws + OFF_MATF))[cB] = make_float4(MaB, McB, MdB, 0.f);
  } else {
    const int topA = cA * Ln3 + Ln3 - 1;      // topB = topA + 16
    const bool lastB = (cB == NC3 - 1);
    float vA0 = 0.05f, vA1 = 0.05f, vA2 = 0.05f;
    float vB0 = 0.05f, vB1 = 0.05f, vB2 = 0.05f;
    float svA = reduce8(fmaf(0.5f, vA2, vA0 + vA1));      // = 1.0
    float AA = (svA > TINY) ? FRCP(svA) : 1.0f;           // A = iV
    float rhoA = 1.0f;
    float AB = AA;
    float rhoB = 1.0f;

    const float* pA = E + (ptrdiff_t)(topA + 8) * 20;
    float eA0a = pA[j], eA1a = pA[s1i], eA2a = pA[s2i]; pA -= 20;
    float eA0b = pA[j], eA1b = pA[s1i], eA2b = pA[s2i]; pA -= 20;
    float eA0c = pA[j], eA1c = pA[s1i], eA2c = pA[s2i]; pA -= 20;
    const float* pB = E + (ptrdiff_t)(topA + 24) * 20;
    float eB0a = pB[j], eB1a = pB[s1i], eB2a = pB[s2i]; pB -= 20;
    float eB0b = pB[j], eB1b = pB[s1i], eB2b = pB[s2i]; pB -= 20;
    float eB0c = pB[j], eB1c = pB[s1i], eB2c = pB[s2i]; pB -= 20;

    for (int i = 0; i < 23; ++i) {
      const int r = topA + 7 - i;             // chain B row = r + 16
      const bool initB = lastB && ((r + 16) == Tn - 2);
      float wA0 = vA0 * eA0a, wA1 = vA1 * eA1a, wA2 = vA2 * eA2a;
      float vb0 = initB ? 0.05f : vB0;
      float vb1 = initB ? 0.05f : vB1;
      float vb2 = initB ? 0.05f : vB2;
      float wB0 = vb0 * eB0a, wB1 = vb1 * eB1a, wB2 = vb2 * eB2a;
      float accA0, accA1, accA2, accB0, accB1, accB2;
      xmv(wA0, wA1, wA2, accA0, accA1, accA2);
      xmv(wB0, wB1, wB2, accB0, accB1, accB2);
      float rhoBe = initB ? 1.0f : rhoB;
      vA0 = accA0 * rhoA; vA1 = accA1 * rhoA; vA2 = accA2 * rhoA;
      vB0 = accB0 * rhoBe; vB1 = accB1 * rhoBe; vB2 = accB2 * rhoBe;
      eA0a = eA0b; eA0b = eA0c; eA0c = pA[j];
      eA1a = eA1b; eA1b = eA1c; eA1c = pA[s1i];
      eA2a = eA2b; eA2b = eA2c; eA2c = pA[s2i]; pA -= 20;
      eB0a = eB0b; eB0b = eB0c; eB0c = pB[j];
      eB1a = eB1b; eB1b = eB1c; eB1c = pB[s1i];
      eB2a = eB2b; eB2b = eB2c; eB2c = pB[s2i]; pB -= 20;
      float sA = reduce8(fmaf(0.5f, vA2, vA0 + vA1));
      float sB = reduce8(fmaf(0.5f, vB2, vB0 + vB1));
      float mnA = sA * AA;
      float mnB = sB * (initB ? 1.0f : AB);
      float iVnA = (sA > TINY) ? FRCP(sA) : 1.0f;
      float iVnB = (sB > TINY) ? FRCP(sB) : 1.0f;
      if (sA <= TINY) { vA0 = vA1 = vA2 = 0.05f; }
      if (sB <= TINY) { vB0 = vB1 = vB2 = 0.05f; }
      if (i >= 7) {
        const int lr = 22 - i;
        mArr[r + 1] = mnA;
        mobius(mnA, MaA, McA, MdA);
        uSA[lr*12 + j] = packh2(vA0 * iVnA, vA1 * iVnA);
        uSA[lr*12 + 8 + q] = packh2(vA2 * iVnA, 0.f);
        if (!lastB || i >= 8) {
          mArr[r + 17] = mnB;
          mobius(mnB, MaB, McB, MdB);
          uSB[lr*12 + j] = packh2(vB0 * iVnB, vB1 * iVnB);
          uSB[lr*12 + 8 + q] = packh2(vB2 * iVnB, 0.f);
        }
      }
      AA = mnA * iVnA; AB = mnB * iVnB;
      rhoA = (mnA > TINY) ? FRCP(mnA) : 1.0f;
      rhoB = (mnB > TINY) ? FRCP(mnB) : 1.0f;
    }
    ((float4*)(ws + OFF_MATB))[NC3 - 1 - cA] = make_float4(MaA, McA, MdA, 0.f);
    ((float4*)(ws + OFF_MATB))[NC3 - 1 - cB] = make_float4(MaB, McB, MdB, 0.f);
  }
}

// ============================ combine ============================
__global__ __launch_bounds__(1024) void combine4_kernel(float* ws, float* out)
{
  __shared__ float wag[16][3];
  __shared__ float wpre[16][3];
  const bool isF = (blockIdx.x == 0);
  const float4* M4 = (const float4*)(ws + (isF ? OFF_MATF : OFF_MATB));
  float* sArr = ws + (isF ? OFF_SF : OFF_SB);
  const float s0 = isF ? 1.0f : 20.0f;
  constexpr int PG = NC3 / 1024;   // 16
  const int tid  = threadIdx.x;
  const int lane = tid & 63;
  const int wid  = tid >> 6;

  float4 mm[PG];
#pragma unroll
  for (int i = 0; i < PG; ++i) mm[i] = M4[tid*PG + i];

  float a = 1.f, cc = 0.f, d = 1.f;
#pragma unroll
  for (int i = 0; i < PG; ++i) {
    float na = mm[i].x * a;
    float nc = fmaf(mm[i].y, a, mm[i].z * cc);
    float nd = mm[i].z * d;
    float mx = fmaxf(na, fmaxf(nc, nd));
    float lam = (mx > 0.f) ? FRCP(mx) : 1.0f;
    a = na*lam; cc = nc*lam; d = nd*lam;
  }

  float ia = a, ic = cc, id = d;
  for (int off = 1; off < 64; off <<= 1) {
    float pa = __shfl_up(ia, off, 64);
    float pc = __shfl_up(ic, off, 64);
    float pd = __shfl_up(id, off, 64);
    if (lane >= off) {
      float na = ia * pa;
      float nc = fmaf(ic, pa, id * pc);
      float nd = id * pd;
      float mx = fmaxf(na, fmaxf(nc, nd));
      float lam = (mx > 0.f) ? FRCP(mx) : 1.0f;
      ia = na*lam; ic = nc*lam; id = nd*lam;
    }
  }
  if (lane == 63) { wag[wid][0] = ia; wag[wid][1] = ic; wag[wid][2] = id; }
  __syncthreads();

  if (tid == 0) {
    float ea = 1.f, ec = 0.f, ed = 1.f;
#pragma unroll
    for (int w = 0; w < 16; ++w) {
      wpre[w][0] = ea; wpre[w][1] = ec; wpre[w][2] = ed;
      float na = wag[w][0] * ea;
      float nc = fmaf(wag[w][1], ea, wag[w][2] * ec);
      float nd = wag[w][2] * ed;
      float mx = fmaxf(na, fmaxf(nc, nd));
      float lam = (mx > 0.f) ? FRCP(mx) : 1.0f;
      ea = na*lam; ec = nc*lam; ed = nd*lam;
    }
    if (isF) {
      float den = fmaf(ec, s0, ed);
      float sfin = (den > 0.f) ? (ea * s0)/den : 0.f;
      out[(size_t)2 * Tn * Kn] = logf(sfin + EPSF);
    }
  }
  __syncthreads();

  float ea = __shfl_up(ia, 1, 64);
  float ec = __shfl_up(ic, 1, 64);
  float ed = __shfl_up(id, 1, 64);
  if (lane == 0) { ea = 1.f; ec = 0.f; ed = 1.f; }
  float pa = wpre[wid][0], pc = wpre[wid][1], pd = wpre[wid][2];
  float xa = ea * pa;
  float xc = fmaf(ec, pa, ed * pc);
  float xd = ed * pd;

  float num = xa * s0, den = fmaf(xc, s0, xd);
  float s = (den > 0.f) ? num/den : 0.f;
#pragma unroll
  for (int i = 0; i < PG; ++i) {
    sArr[tid*PG + i] = s;
    float nn = mm[i].x * s, dd = fmaf(mm[i].y, s, mm[i].z);
    s = (dd > 0.f) ? nn/dd : 0.f;
  }
}

// ============================ scale ============================
// 128 thr = 8 groups x 16 lanes; lane ll handles one t-row of its chunk.
__global__ __launch_bounds__(128) void scale4_kernel(float* ws, float* out)
{
  const int tid = threadIdx.x;
  const int g   = tid >> 4;
  const int ll  = tid & 15;
  const bool isF = ((int)blockIdx.x < NBSC);
  const int c = (isF ? (int)blockIdx.x : (int)blockIdx.x - NBSC) * 8 + g;
  float* base = out + (isF ? (size_t)0 : (size_t)Tn * Kn) + (size_t)c * SPC;
  const unsigned* uS = (const unsigned*)base;

  float mySig = 1.0f;
  if (isF) {
    const float* mA = ws + OFF_MF;
    float s = ws[OFF_SF + c];
    const int t0 = c * Ln3;
#pragma unroll
    for (int i = 0; i < Ln3; ++i) {
      float z = s * mA[t0 + i];
      float sn = z * FRCP(z + EPSF);
      if (i == ll) mySig = sn;
      s = sn;
    }
  } else {
    const float* mA = ws + OFF_MB;
    float s = ws[OFF_SB + (NC3 - 1 - c)];
    const int top = c * Ln3 + Ln3 - 1;
#pragma unroll
    for (int i = 0; i < Ln3; ++i) {
      int r = top - i;
      float sn;
      if (r == Tn - 1) sn = s;
      else {
        float z = s * mA[r + 1];
        sn = z * FRCP(z + EPSF);
      }
      if (i == Ln3 - 1 - ll) mySig = sn;
      s = sn;
    }
  }

  uint4 ua = ((const uint4*)(uS + ll*12))[0];
  uint4 ub = ((const uint4*)(uS + ll*12))[1];
  uint4 uc = ((const uint4*)(uS + ll*12))[2];
  __syncthreads();   // staged reads complete before f32 overwrites

  const bool onesRow = (!isF && c == NC3 - 1 && ll == Ln3 - 1);
  float sg = mySig;
  unsigned slots[12] = {ua.x,ua.y,ua.z,ua.w, ub.x,ub.y,ub.z,ub.w, uc.x,uc.y,uc.z,uc.w};
  float o[20];
#pragma unroll
  for (int jj = 0; jj < 8; ++jj) {
    __half2 h2 = *(__half2*)&slots[jj];
    float2 f2 = __half22float2(h2);
    o[jj]     = f2.x * sg;
    o[8 + jj] = f2.y * sg;
  }
#pragma unroll
  for (int qq = 0; qq < 4; ++qq) {
    __half2 h2 = *(__half2*)&slots[8 + qq];
    float2 f2 = __half22float2(h2);
    o[16 + qq] = f2.x * sg;
  }
  if (onesRow) {
#pragma unroll
    for (int k = 0; k < 20; ++k) o[k] = 1.0f;
  }
  float* dst = base + ll * 20;
  *(float4*)&dst[0]  = *(float4*)&o[0];
  *(float4*)&dst[4]  = *(float4*)&o[4];
  *(float4*)&dst[8]  = *(float4*)&o[8];
  *(float4*)&dst[12] = *(float4*)&o[12];
  *(float4*)&dst[16] = *(float4*)&o[16];
}

extern "C" void kernel_launch(void* const* d_in, const int* in_sizes, int n_in,
                              void* d_out, int out_size, void* d_ws, size_t ws_size,
                              hipStream_t stream) {
  const float* obs         = (const float*)d_in[0];
  const float* beta_logits = (const float*)d_in[1];
  const float* pi_logits   = (const float*)d_in[2];
  const float* means       = (const float*)d_in[3];
  const float* log_vars    = (const float*)d_in[4];
  float* out = (float*)d_out;
  float* ws  = (float*)d_ws;

  hipLaunchKernelGGL(emis_kernel, dim3(Tn/64), dim3(320), 0, stream,
                     obs, means, log_vars, ws);
  hipLaunchKernelGGL(scan8_kernel, dim3(2*NBF8), dim3(256), 0, stream,
                     beta_logits, pi_logits, ws, out);
  hipLaunchKernelGGL(combine4_kernel, dim3(2), dim3(1024), 0, stream, ws, out);
  hipLaunchKernelGGL(scale4_kernel, dim3(2*NBSC), dim3(128), 0, stream, ws, out);
}